// Round 1
// baseline (88.061 us; speedup 1.0000x reference)
//
#include <hip/hip_runtime.h>

#define PAD 10
#define CS 128
#define CSP 148           // CS + 2*PAD
#define AH 4000
#define AW 4000
#define N1T 32            // tiles along width

__global__ __launch_bounds__(256) void shift_bicubic_kernel(
    const float* __restrict__ matrix,
    const float* __restrict__ theta,
    float* __restrict__ out)
{
    const int n  = blockIdx.x;        // tile index, 0..1023
    const int i0 = n >> 5;            // tile row
    const int i1 = n & 31;            // tile col
    const int c  = threadIdx.x;                      // 0..127 within tile
    const int r  = blockIdx.y * 2 + threadIdx.y;     // 0..127 within tile
    const int h  = i0 * CS + r;
    const int w  = i1 * CS + c;
    if (h >= AH || w >= AW) return;

    const float t00 = theta[n*6+0], t01 = theta[n*6+1], t02 = theta[n*6+2];
    const float t10 = theta[n*6+3], t11 = theta[n*6+4], t12 = theta[n*6+5];

    // tile-local sample pixel
    const float px = (float)(c + PAD);
    const float py = (float)(r + PAD);
    const float xs = (2.0f*px + 1.0f) * (1.0f/148.0f) - 1.0f;
    const float ys = (2.0f*py + 1.0f) * (1.0f/148.0f) - 1.0f;
    const float gx = t00*xs + t01*ys + t02;
    const float gy = t10*xs + t11*ys + t12;
    const float ix = ((gx + 1.0f)*148.0f - 1.0f)*0.5f;
    const float iy = ((gy + 1.0f)*148.0f - 1.0f)*0.5f;

    const float fx0 = floorf(ix);
    const float fy0 = floorf(iy);
    const float tx  = ix - fx0;
    const float ty  = iy - fy0;
    const int  ixi  = (int)fx0;
    const int  iyi  = (int)fy0;

    // Keys cubic weights, A = -0.75 (PyTorch bicubic)
    float wx[4], wy[4];
    {
        const float A_ = -0.75f;
        float t2 = tx*tx, t3 = t2*tx;
        wx[0] = A_*(t3 - 2.0f*t2 + tx);
        wx[1] = (A_+2.0f)*t3 - (A_+3.0f)*t2 + 1.0f;
        float s = 1.0f - tx, s2 = s*s, s3 = s2*s;
        wx[2] = (A_+2.0f)*s3 - (A_+3.0f)*s2 + 1.0f;
        wx[3] = A_*(s3 - 2.0f*s2 + s);
        t2 = ty*ty; t3 = t2*ty;
        wy[0] = A_*(t3 - 2.0f*t2 + ty);
        wy[1] = (A_+2.0f)*t3 - (A_+3.0f)*t2 + 1.0f;
        s = 1.0f - ty; s2 = s*s; s3 = s2*s;
        wy[2] = (A_+2.0f)*s3 - (A_+3.0f)*s2 + 1.0f;
        wy[3] = A_*(s3 - 2.0f*s2 + s);
    }

    // tile (0,0) in matrix coords
    const int gr0 = i0*CS - 2*PAD;
    const int gc0 = i1*CS - 2*PAD;

    float acc = 0.0f;
    #pragma unroll
    for (int ky = 0; ky < 4; ++ky) {
        const int row = iyi - 1 + ky;
        const int gr  = gr0 + row;
        const bool rok = (row >= 0) & (row < CSP) & (gr >= 0) & (gr < AH);
        if (!rok) continue;
        const float* rp = matrix + (size_t)gr * AW;
        float racc = 0.0f;
        #pragma unroll
        for (int kx = 0; kx < 4; ++kx) {
            const int col = ixi - 1 + kx;
            const int gc  = gc0 + col;
            const bool cok = (col >= 0) & (col < CSP) & (gc >= 0) & (gc < AW);
            const float v = cok ? rp[gc] : 0.0f;
            racc = fmaf(wx[kx], v, racc);
        }
        acc = fmaf(wy[ky], racc, acc);
    }
    out[(size_t)h * AW + w] = acc;
}

extern "C" void kernel_launch(void* const* d_in, const int* in_sizes, int n_in,
                              void* d_out, int out_size, void* d_ws, size_t ws_size,
                              hipStream_t stream) {
    const float* matrix = (const float*)d_in[0];
    const float* theta  = (const float*)d_in[1];
    float* out = (float*)d_out;

    dim3 block(128, 2, 1);     // one 128-wide tile row pair per block
    dim3 grid(1024, 64, 1);    // 1024 tiles × 64 row-pairs
    shift_bicubic_kernel<<<grid, block, 0, stream>>>(matrix, theta, out);
}

// Round 2
// 81.984 us; speedup vs baseline: 1.0741x; 1.0741x over previous
//
#include <hip/hip_runtime.h>

#define PAD 10
#define CS 128
#define CSP 148           // CS + 2*PAD
#define AH 4000
#define AW 4000

__global__ __launch_bounds__(256) void shift_bicubic_kernel(
    const float* __restrict__ matrix,
    const float* __restrict__ theta,
    float* __restrict__ out)
{
    const int n  = blockIdx.x;        // tile index, 0..1023
    const int i0 = n >> 5;            // tile row
    const int i1 = n & 31;            // tile col
    const int c  = threadIdx.x;                      // 0..127 within tile
    const int r  = blockIdx.y * 2 + threadIdx.y;     // 0..127 within tile
    const int h  = i0 * CS + r;
    const int w  = i1 * CS + c;
    if (h >= AH || w >= AW) return;

    const float t00 = theta[n*6+0], t01 = theta[n*6+1], t02 = theta[n*6+2];
    const float t10 = theta[n*6+3], t11 = theta[n*6+4], t12 = theta[n*6+5];

    // tile-local sample pixel
    const float px = (float)(c + PAD);
    const float py = (float)(r + PAD);
    const float xs = (2.0f*px + 1.0f) * (1.0f/148.0f) - 1.0f;
    const float ys = (2.0f*py + 1.0f) * (1.0f/148.0f) - 1.0f;
    const float gx = t00*xs + t01*ys + t02;
    const float gy = t10*xs + t11*ys + t12;
    const float ix = ((gx + 1.0f)*148.0f - 1.0f)*0.5f;
    const float iy = ((gy + 1.0f)*148.0f - 1.0f)*0.5f;

    const float fx0 = floorf(ix);
    const float fy0 = floorf(iy);
    const float tx  = ix - fx0;
    const float ty  = iy - fy0;
    const int  ixi  = (int)fx0;
    const int  iyi  = (int)fy0;

    // Keys cubic weights, A = -0.75 (PyTorch bicubic)
    float wx0, wx1, wx2, wx3, wy0, wy1, wy2, wy3;
    {
        const float A_ = -0.75f;
        float t2 = tx*tx, t3 = t2*tx;
        wx0 = A_*(t3 - 2.0f*t2 + tx);
        wx1 = (A_+2.0f)*t3 - (A_+3.0f)*t2 + 1.0f;
        float s = 1.0f - tx, s2 = s*s, s3 = s2*s;
        wx2 = (A_+2.0f)*s3 - (A_+3.0f)*s2 + 1.0f;
        wx3 = A_*(s3 - 2.0f*s2 + s);
        t2 = ty*ty; t3 = t2*ty;
        wy0 = A_*(t3 - 2.0f*t2 + ty);
        wy1 = (A_+2.0f)*t3 - (A_+3.0f)*t2 + 1.0f;
        s = 1.0f - ty; s2 = s*s; s3 = s2*s;
        wy2 = (A_+2.0f)*s3 - (A_+3.0f)*s2 + 1.0f;
        wy3 = A_*(s3 - 2.0f*s2 + s);
    }

    // tile (0,0) in matrix coords
    const int gr0 = i0*CS - 2*PAD;
    const int gc0 = i1*CS - 2*PAD;

    // block-uniform merged limits: valid tile-local index range where the
    // tile window has data (inside tile AND inside matrix)
    const int lo_c = (gc0 < 0) ? -gc0 : 0;
    const int hi_c = (gc0 + CSP - 1 > AW - 1) ? (AW - 1 - gc0) : (CSP - 1);
    const int lo_r = (gr0 < 0) ? -gr0 : 0;
    const int hi_r = (gr0 + CSP - 1 > AH - 1) ? (AH - 1 - gr0) : (CSP - 1);

    float acc;
    const bool fast = (ixi - 1 >= lo_c) & (ixi + 2 <= hi_c) &
                      (iyi - 1 >= lo_r) & (iyi + 2 <= hi_r);
    if (fast) {
        const float* p = matrix + (size_t)(gr0 + iyi - 1) * AW + (gc0 + ixi - 1);
        float4 r0, r1, r2, r3;
        __builtin_memcpy(&r0, p,          16);
        __builtin_memcpy(&r1, p + AW,     16);
        __builtin_memcpy(&r2, p + 2*AW,   16);
        __builtin_memcpy(&r3, p + 3*AW,   16);
        float a0 = fmaf(wx3, r0.w, fmaf(wx2, r0.z, fmaf(wx1, r0.y, wx0*r0.x)));
        float a1 = fmaf(wx3, r1.w, fmaf(wx2, r1.z, fmaf(wx1, r1.y, wx0*r1.x)));
        float a2 = fmaf(wx3, r2.w, fmaf(wx2, r2.z, fmaf(wx1, r2.y, wx0*r2.x)));
        float a3 = fmaf(wx3, r3.w, fmaf(wx2, r3.z, fmaf(wx1, r3.y, wx0*r3.x)));
        acc = fmaf(wy3, a3, fmaf(wy2, a2, fmaf(wy1, a1, wy0*a0)));
    } else {
        acc = 0.0f;
        #pragma unroll
        for (int ky = 0; ky < 4; ++ky) {
            const int row = iyi - 1 + ky;
            const int gr  = gr0 + row;
            const bool rok = (row >= 0) & (row < CSP) & (gr >= 0) & (gr < AH);
            if (!rok) continue;
            const float* rp = matrix + (size_t)gr * AW;
            float racc = 0.0f;
            #pragma unroll
            for (int kx = 0; kx < 4; ++kx) {
                const int col = ixi - 1 + kx;
                const int gc  = gc0 + col;
                const bool cok = (col >= 0) & (col < CSP) & (gc >= 0) & (gc < AW);
                const float v = cok ? rp[gc] : 0.0f;
                racc = fmaf(wx0 * (kx==0) + wx1 * (kx==1) + wx2 * (kx==2) + wx3 * (kx==3), v, racc);
            }
            acc = fmaf(wy0 * (ky==0) + wy1 * (ky==1) + wy2 * (ky==2) + wy3 * (ky==3), racc, acc);
        }
    }
    out[(size_t)h * AW + w] = acc;
}

extern "C" void kernel_launch(void* const* d_in, const int* in_sizes, int n_in,
                              void* d_out, int out_size, void* d_ws, size_t ws_size,
                              hipStream_t stream) {
    const float* matrix = (const float*)d_in[0];
    const float* theta  = (const float*)d_in[1];
    float* out = (float*)d_out;

    dim3 block(128, 2, 1);     // one 128-wide tile row pair per block
    dim3 grid(1024, 64, 1);    // 1024 tiles × 64 row-pairs
    shift_bicubic_kernel<<<grid, block, 0, stream>>>(matrix, theta, out);
}

// Round 3
// 58.538 us; speedup vs baseline: 1.5043x; 1.4005x over previous
//
#include <hip/hip_runtime.h>

#define PAD 10
#define CS 128
#define CSP 148           // CS + 2*PAD
#define AH 4000
#define AW 4000
#define RPT 4             // output rows per thread

__global__ __launch_bounds__(256) void shift_bicubic_kernel(
    const float* __restrict__ matrix,
    const float* __restrict__ theta,
    float* __restrict__ out)
{
    const int n   = blockIdx.x;          // tile index 0..1023
    const int i0  = n >> 5;              // tile row
    const int i1  = n & 31;              // tile col
    const int c   = threadIdx.x & 127;   // column within tile
    const int sub = threadIdx.x >> 7;    // 0..1
    const int r0  = blockIdx.y * (2*RPT) + sub*RPT;  // first of 4 rows
    const int w   = i1 * CS + c;
    const int h0  = i0 * CS + r0;
    if (w >= AW || h0 >= AH) return;

    const float t00 = theta[n*6+0], t01 = theta[n*6+1], t02 = theta[n*6+2];
    const float t10 = theta[n*6+3], t11 = theta[n*6+4], t12 = theta[n*6+5];

    const float xs  = (2.0f*(float)(c + PAD) + 1.0f) * (1.0f/148.0f) - 1.0f;
    const float ys0 = (2.0f*(float)(r0 + PAD) + 1.0f) * (1.0f/148.0f) - 1.0f;
    const float bx  = fmaf(t00, xs, t02);   // x-part of gx
    const float by  = fmaf(t10, xs, t12);   // x-part of gy

    // tile (0,0) in matrix coords
    const int gr0 = i0*CS - 2*PAD;
    const int gc0 = i1*CS - 2*PAD;

    // block-uniform merged limits (inside tile window AND inside matrix)
    const int lo_c = (gc0 < 0) ? -gc0 : 0;
    const int hi_c = (gc0 + CSP - 1 > AW - 1) ? (AW - 1 - gc0) : (CSP - 1);
    const int lo_r = (gr0 < 0) ? -gr0 : 0;
    const int hi_r = (gr0 + CSP - 1 > AH - 1) ? (AH - 1 - gr0) : (CSP - 1);

    const int base_el = gr0*AW + gc0;    // may be negative; fast path result >= 0
    int oidx = h0*AW + w;

    #pragma unroll
    for (int k = 0; k < RPT; ++k) {
        const float ysk = fmaf((float)k, 2.0f/148.0f, ys0);
        const float gx  = fmaf(t01, ysk, bx);
        const float gy  = fmaf(t11, ysk, by);
        const float ixf = fmaf(gx, 74.0f, 73.5f);   // ((gx+1)*148-1)/2
        const float iyf = fmaf(gy, 74.0f, 73.5f);

        const float fx0 = floorf(ixf);
        const float fy0 = floorf(iyf);
        const float tx  = ixf - fx0;
        const float ty  = iyf - fy0;
        const int  ixi  = (int)fx0;
        const int  iyi  = (int)fy0;

        // Keys cubic weights, A=-0.75: w0=A*t*s^2, w3=A*s*t^2 (s=1-t),
        // w1=1+t^2*((A+2)t-(A+3)), w2 symmetric.
        const float A_ = -0.75f, AP2 = 1.25f, mAP3 = -2.25f;
        const float sx = 1.0f - tx, sy = 1.0f - ty;
        const float tx2 = tx*tx, sx2 = sx*sx;
        const float ty2 = ty*ty, sy2 = sy*sy;
        const float wx0 = A_*(tx*sx2);
        const float wx3 = A_*(sx*tx2);
        const float wx1 = fmaf(tx2, fmaf(AP2, tx, mAP3), 1.0f);
        const float wx2 = fmaf(sx2, fmaf(AP2, sx, mAP3), 1.0f);
        const float wy0 = A_*(ty*sy2);
        const float wy3 = A_*(sy*ty2);
        const float wy1 = fmaf(ty2, fmaf(AP2, ty, mAP3), 1.0f);
        const float wy2 = fmaf(sy2, fmaf(AP2, sy, mAP3), 1.0f);

        float acc;
        const bool fast = (ixi - 1 >= lo_c) & (ixi + 2 <= hi_c) &
                          (iyi - 1 >= lo_r) & (iyi + 2 <= hi_r);
        if (fast) {
            const float* p = matrix + (base_el + (iyi - 1)*AW + (ixi - 1));
            float4 q0, q1, q2, q3;
            __builtin_memcpy(&q0, p,        16);
            __builtin_memcpy(&q1, p + AW,   16);
            __builtin_memcpy(&q2, p + 2*AW, 16);
            __builtin_memcpy(&q3, p + 3*AW, 16);
            const float a0 = fmaf(wx3,q0.w, fmaf(wx2,q0.z, fmaf(wx1,q0.y, wx0*q0.x)));
            const float a1 = fmaf(wx3,q1.w, fmaf(wx2,q1.z, fmaf(wx1,q1.y, wx0*q1.x)));
            const float a2 = fmaf(wx3,q2.w, fmaf(wx2,q2.z, fmaf(wx1,q2.y, wx0*q2.x)));
            const float a3 = fmaf(wx3,q3.w, fmaf(wx2,q3.z, fmaf(wx1,q3.y, wx0*q3.x)));
            acc = fmaf(wy3,a3, fmaf(wy2,a2, fmaf(wy1,a1, wy0*a0)));
        } else {
            const float wxa[4] = {wx0, wx1, wx2, wx3};
            const float wya[4] = {wy0, wy1, wy2, wy3};
            acc = 0.0f;
            #pragma unroll
            for (int ky = 0; ky < 4; ++ky) {
                const int row = iyi - 1 + ky;
                const int gr  = gr0 + row;
                const bool rok = (row >= 0) & (row < CSP) & (gr >= 0) & (gr < AH);
                float racc = 0.0f;
                #pragma unroll
                for (int kx = 0; kx < 4; ++kx) {
                    const int col = ixi - 1 + kx;
                    const int gc  = gc0 + col;
                    const bool cok = rok & (col >= 0) & (col < CSP) & (gc >= 0) & (gc < AW);
                    const float v = cok ? matrix[(size_t)gr*AW + gc] : 0.0f;
                    racc = fmaf(wxa[kx], v, racc);
                }
                acc = fmaf(wya[ky], racc, acc);
            }
        }
        if (h0 + k < AH) __builtin_nontemporal_store(acc, &out[oidx]);
        oidx += AW;
    }
}

extern "C" void kernel_launch(void* const* d_in, const int* in_sizes, int n_in,
                              void* d_out, int out_size, void* d_ws, size_t ws_size,
                              hipStream_t stream) {
    const float* matrix = (const float*)d_in[0];
    const float* theta  = (const float*)d_in[1];
    float* out = (float*)d_out;

    dim3 block(256, 1, 1);
    dim3 grid(1024, CS/(2*RPT), 1);   // 1024 tiles x 16 row-groups (8 rows each)
    shift_bicubic_kernel<<<grid, block, 0, stream>>>(matrix, theta, out);
}